// Round 3
// baseline (337.128 us; speedup 1.0000x reference)
//
#include <hip/hip_runtime.h>
#include <hip/hip_bf16.h>
#include <math.h>

#define CN 64
#define CG 128
#define CS 64
#define EPSV 1e-5f
#define ASTRIDE 28   // A row stride (27 taps + 1 pad, 16B-aligned)

#define BINW 512     // j-rows per bin
#define BINSH 9
#define BCAP 8192    // entry capacity per bin (avg ~6900, 15-sigma headroom)
#define ECH 2048     // entries per k_hist/k_route block (8 rounds x 256)

#define FROWS 64     // rows per k_fuse block

__device__ __forceinline__ float4 ld4(const float* p){ return *(const float4*)p; }
__device__ __forceinline__ void st4(float* p, float4 v){ *(float4*)p = v; }

// ---------------- GEMM: Y = X[gather?] @ W, plus per-channel sum/sumsq ----------------
template<int CK, bool GATHER>
__global__ void __launch_bounds__(256) k_gemm(
    const float* __restrict__ X, const int* __restrict__ gidx,
    const float* __restrict__ W,
    float* __restrict__ Y, float* __restrict__ sum, float* __restrict__ sumsq, int Ng)
{
    __shared__ float Wl[CK*CN];
    __shared__ float Xl[64*68];
    int t = threadIdx.x;
    for (int idx = t; idx < CK*CN/4; idx += 256)
        ((float4*)Wl)[idx] = ((const float4*)W)[idx];

    int row0 = blockIdx.x * 64;
    int cg = t & 15, rg = t >> 4;
    int c0 = cg*4, r0 = rg*4;
    float4 acc[4];
    #pragma unroll
    for (int rr=0;rr<4;rr++) acc[rr] = make_float4(0.f,0.f,0.f,0.f);

    for (int kc = 0; kc < CK; kc += 64){
        for (int idx = t; idx < 64*16; idx += 256){
            int r = idx >> 4;
            int c4 = idx & 15;
            float4 v = make_float4(0.f,0.f,0.f,0.f);
            int row = row0 + r;
            if (row < Ng){
                int src = GATHER ? gidx[row] : row;
                v = ((const float4*)(X + (size_t)src*CK + kc))[c4];
            }
            *(float4*)&Xl[r*68 + c4*4] = v;
        }
        __syncthreads();
        for (int k = 0; k < 64; k += 4){
            float4 w0 = ld4(&Wl[(kc+k+0)*CN + c0]);
            float4 w1 = ld4(&Wl[(kc+k+1)*CN + c0]);
            float4 w2 = ld4(&Wl[(kc+k+2)*CN + c0]);
            float4 w3 = ld4(&Wl[(kc+k+3)*CN + c0]);
            #pragma unroll
            for (int rr=0;rr<4;rr++){
                float4 xv = ld4(&Xl[(r0+rr)*68 + k]);
                acc[rr].x = fmaf(xv.x,w0.x, fmaf(xv.y,w1.x, fmaf(xv.z,w2.x, fmaf(xv.w,w3.x, acc[rr].x))));
                acc[rr].y = fmaf(xv.x,w0.y, fmaf(xv.y,w1.y, fmaf(xv.z,w2.y, fmaf(xv.w,w3.y, acc[rr].y))));
                acc[rr].z = fmaf(xv.x,w0.z, fmaf(xv.y,w1.z, fmaf(xv.z,w2.z, fmaf(xv.w,w3.z, acc[rr].z))));
                acc[rr].w = fmaf(xv.x,w0.w, fmaf(xv.y,w1.w, fmaf(xv.z,w2.w, fmaf(xv.w,w3.w, acc[rr].w))));
            }
        }
        __syncthreads();
    }

    float4 s4 = make_float4(0.f,0.f,0.f,0.f), q4 = make_float4(0.f,0.f,0.f,0.f);
    #pragma unroll
    for (int rr=0;rr<4;rr++){
        int row = row0 + r0 + rr;
        if (row < Ng) st4(Y + (size_t)row*CN + c0, acc[rr]);
        s4.x += acc[rr].x; s4.y += acc[rr].y; s4.z += acc[rr].z; s4.w += acc[rr].w;
        q4.x += acc[rr].x*acc[rr].x; q4.y += acc[rr].y*acc[rr].y;
        q4.z += acc[rr].z*acc[rr].z; q4.w += acc[rr].w*acc[rr].w;
    }
    float* red = Xl;
    __syncthreads();
    st4(red + rg*64 + c0, s4);
    st4(red + 1024 + rg*64 + c0, q4);
    __syncthreads();
    if (t < 64){
        float ss = 0.f, qq = 0.f;
        #pragma unroll
        for (int r=0;r<16;r++){ ss += red[r*64 + t]; qq += red[1024 + r*64 + t]; }
        atomicAdd(&sum[t], ss); atomicAdd(&sumsq[t], qq);
    }
}

__device__ __forceinline__ void bnparams(float4 s, float4 q, float4 gam, float4 bet,
                                         float invN, float4& scl, float4& sft)
{
    float mux = s.x*invN, muy = s.y*invN, muz = s.z*invN, muw = s.w*invN;
    float vx = q.x*invN - mux*mux, vy = q.y*invN - muy*muy;
    float vz = q.z*invN - muz*muz, vw = q.w*invN - muw*muw;
    scl = make_float4(gam.x*rsqrtf(vx+EPSV), gam.y*rsqrtf(vy+EPSV),
                      gam.z*rsqrtf(vz+EPSV), gam.w*rsqrtf(vw+EPSV));
    sft = make_float4(bet.x - mux*scl.x, bet.y - muy*scl.y,
                      bet.z - muz*scl.z, bet.w - muw*scl.w);
}

// --------- fuse: w[i] = relu(relu(BN(Yg)) + relu(BN(Ys))) @ Wc; per-block partial sum/sumsq ---------
__global__ void __launch_bounds__(256) k_fuse(
    const float* __restrict__ Yg, const float* __restrict__ Ys,
    const float* __restrict__ stats,
    const float* __restrict__ gamma_g, const float* __restrict__ beta_g,
    const float* __restrict__ gamma_s, const float* __restrict__ beta_s,
    const float* __restrict__ Wc,
    float* __restrict__ w, float* __restrict__ wpart, int Ng)
{
    int t = threadIdx.x; int l = t & 15; int r = t >> 4;
    int c4 = l*4;
    float invN = 1.0f/(float)Ng;
    float4 sclg, sftg, scls, sfts;
    bnparams(ld4(stats + c4),       ld4(stats + 64 + c4),  ld4(gamma_g + c4), ld4(beta_g + c4), invN, sclg, sftg);
    bnparams(ld4(stats + 128 + c4), ld4(stats + 192 + c4), ld4(gamma_s + c4), ld4(beta_s + c4), invN, scls, sfts);
    float4 wc = ld4(Wc + c4);

    int base = blockIdx.x * FROWS;
    float s_acc = 0.f, q_acc = 0.f;
    #pragma unroll
    for (int rr = 0; rr < FROWS/16; ++rr){
        int i = base + rr*16 + r;
        float partial = 0.f;
        if (i < Ng){
            float4 a = ld4(Yg + (size_t)i*CN + c4);
            float4 b = ld4(Ys + (size_t)i*CN + c4);
            float ax = fmaxf(0.f, fmaf(a.x, sclg.x, sftg.x));
            float ay = fmaxf(0.f, fmaf(a.y, sclg.y, sftg.y));
            float az = fmaxf(0.f, fmaf(a.z, sclg.z, sftg.z));
            float aw = fmaxf(0.f, fmaf(a.w, sclg.w, sftg.w));
            float bx = fmaxf(0.f, fmaf(b.x, scls.x, sfts.x));
            float by = fmaxf(0.f, fmaf(b.y, scls.y, sfts.y));
            float bz = fmaxf(0.f, fmaf(b.z, scls.z, sfts.z));
            float bw = fmaxf(0.f, fmaf(b.w, scls.w, sfts.w));
            float sx = fmaxf(0.f, ax+bx), sy = fmaxf(0.f, ay+by);
            float sz = fmaxf(0.f, az+bz), sw = fmaxf(0.f, aw+bw);
            partial = sx*wc.x + sy*wc.y + sz*wc.z + sw*wc.w;
        }
        partial += __shfl_xor(partial, 1);
        partial += __shfl_xor(partial, 2);
        partial += __shfl_xor(partial, 4);
        partial += __shfl_xor(partial, 8);
        if (l == 0){
            if (i < Ng) w[i] = partial;
            s_acc += partial;
            q_acc += partial*partial;
        }
    }
    __shared__ float red[32];
    if (l == 0){ red[r] = s_acc; red[16+r] = q_acc; }
    __syncthreads();
    if (t == 0){
        float s2=0.f,q2=0.f;
        #pragma unroll
        for (int j2=0;j2<16;j2++){ s2+=red[j2]; q2+=red[16+j2]; }
        wpart[2*blockIdx.x]   = s2;
        wpart[2*blockIdx.x+1] = q2;
    }
}

// --------- hist: per-block bin histogram -> histR[blk][bin] (row-major) + histT[bin][blk] (col-major) ---------
__global__ void __launch_bounds__(256) k_hist(
    const int* __restrict__ pout, unsigned* __restrict__ histR,
    unsigned* __restrict__ histT, int E, int NB, int RB)
{
    __shared__ unsigned hist[512];
    int t = threadIdx.x;
    for (int b = t; b < 512; b += 256) hist[b] = 0u;
    __syncthreads();
    int e0 = blockIdx.x * ECH;
    #pragma unroll
    for (int r = 0; r < ECH/256; ++r){
        int e = e0 + r*256 + t;
        if (e < E) atomicAdd(&hist[pout[e] >> BINSH], 1u);
    }
    __syncthreads();
    int blk = blockIdx.x;
    for (int b = t; b < NB; b += 256){
        unsigned h = hist[b];
        histR[(size_t)blk*NB + b] = h;
        histT[(size_t)b*RB + blk] = h;
    }
}

// --------- offs: per-bin exclusive prefix over blocks (deterministic staging offsets, NO atomics) ---------
// block b < NB: scan histT[b][*] -> offs[blk][b]; write gcount[b]=total.
// block b == NB: reduce wpart -> BN scale/shift for the attention sigmoid.
__global__ void __launch_bounds__(256) k_offs(
    const unsigned* __restrict__ histT, unsigned* __restrict__ offs,
    unsigned* __restrict__ gcount,
    const float* __restrict__ wpart, int nf,
    const float* __restrict__ gamma_c, const float* __restrict__ beta_c,
    float* __restrict__ scsh, int RB, int NB, int Ng)
{
    int t = threadIdx.x;
    int b = blockIdx.x;
    if (b == NB){
        __shared__ float r8[8];
        float ls = 0.f, lq = 0.f;
        for (int i = t; i < nf; i += 256){ ls += wpart[2*i]; lq += wpart[2*i+1]; }
        #pragma unroll
        for (int off = 1; off < 64; off <<= 1){
            ls += __shfl_xor(ls, off);
            lq += __shfl_xor(lq, off);
        }
        if ((t & 63) == 0){ r8[t>>6] = ls; r8[4 + (t>>6)] = lq; }
        __syncthreads();
        if (t == 0){
            float S = r8[0]+r8[1]+r8[2]+r8[3];
            float Q = r8[4]+r8[5]+r8[6]+r8[7];
            float invN = 1.0f/(float)Ng;
            float mu = S*invN;
            float var = Q*invN - mu*mu;
            float sc = gamma_c[0]*rsqrtf(var+EPSV);
            scsh[0] = sc;
            scsh[1] = beta_c[0] - mu*sc;
        }
        return;
    }
    // RB <= 2048 assumed (E=2.7M, ECH=2048 -> RB=1319)
    __shared__ unsigned sv[2048];
    __shared__ unsigned pA[256];
    __shared__ unsigned pB[256];
    const unsigned* col = histT + (size_t)b*RB;
    for (int i = t; i < RB; i += 256) sv[i] = col[i];
    __syncthreads();
    int chunk = (RB + 255) / 256;
    int i0 = t*chunk;
    unsigned s = 0u;
    for (int c = 0; c < chunk; ++c){ int i = i0 + c; if (i < RB) s += sv[i]; }
    pA[t] = s;
    __syncthreads();
    unsigned* srcp = pA; unsigned* dstp = pB;
    for (int off = 1; off < 256; off <<= 1){
        unsigned v = srcp[t];
        if (t >= off) v += srcp[t-off];
        dstp[t] = v;
        __syncthreads();
        unsigned* tmp = srcp; srcp = dstp; dstp = tmp;
    }
    unsigned run = (t == 0) ? 0u : srcp[t-1];
    for (int c = 0; c < chunk; ++c){
        int i = i0 + c;
        if (i < RB){ offs[(size_t)i*NB + b] = run; run += sv[i]; }
    }
    if (t == 255) gcount[b] = srcp[255];
}

// --------- route: deterministic binned scatter. Zero global atomics. ---------
// Loads its histogram row + exact offsets; LDS scan -> bin-ordered LDS staging; coalesced flush.
__global__ void __launch_bounds__(256) k_route(
    const int* __restrict__ pin, const int* __restrict__ pout,
    const float* __restrict__ w, const float* __restrict__ scsh,
    const unsigned* __restrict__ offs, const unsigned* __restrict__ histR,
    uint2* __restrict__ staging, int E, int P, int NB)
{
    __shared__ unsigned hist[512];
    __shared__ unsigned gbase[512];
    __shared__ unsigned lbase[512];
    __shared__ unsigned rank2[512];
    __shared__ unsigned scn[2][512];
    __shared__ unsigned s_dst[ECH];
    __shared__ uint2 s_uv[ECH];

    int t = threadIdx.x, blk = blockIdx.x;
    for (int b = t; b < 512; b += 256){
        unsigned h = (b < NB) ? histR[(size_t)blk*NB + b] : 0u;
        hist[b] = h; scn[0][b] = h; rank2[b] = 0u;
        gbase[b] = (b < NB) ? offs[(size_t)blk*NB + b] : 0u;
    }
    __syncthreads();

    int src = 0;
    for (int off = 1; off < 512; off <<= 1){
        for (int i = t; i < 512; i += 256){
            unsigned v = scn[src][i];
            if (i >= off) v += scn[src][i-off];
            scn[src^1][i] = v;
        }
        __syncthreads();
        src ^= 1;
    }
    for (int b = t; b < 512; b += 256) lbase[b] = scn[src][b] - hist[b];

    float sc = scsh[0], sh = scsh[1];
    int e0 = blk * ECH;
    int k0 = e0 / P;                 // one divide per thread (ECH < P assumed)
    int rem0 = e0 - k0*P;
    __syncthreads();

    // pass B: compute att inline, assign deterministic slots (bin-ordered in LDS)
    #pragma unroll
    for (int r = 0; r < ECH/256; ++r){
        int L = r*256 + t;
        int e = e0 + L;
        if (e < E){
            int j = pout[e];
            int i = pin[e];
            int b = j >> BINSH;
            float z = fmaf(sc, w[i], sh);
            float att = 1.0f/(1.0f+__expf(-z));
            int k = k0; if (rem0 + L >= P) k++;
            unsigned rk = atomicAdd(&rank2[b], 1u);
            unsigned slot = lbase[b] + rk;
            unsigned d = gbase[b] + rk;
            if (d < BCAP){
                s_uv[slot] = make_uint2(__float_as_uint(att),
                                        ((unsigned)(j & (BINW-1)) << 5) | (unsigned)k);
                s_dst[slot] = (unsigned)b*BCAP + d;
            } else {
                s_dst[slot] = 0xFFFFFFFFu;   // statistically impossible overflow: drop
            }
        }
    }
    __syncthreads();

    // pass C: pure coalesced flush of bin-ordered runs
    int nval = min(ECH, E - e0);
    for (int idx = t; idx < nval; idx += 256){
        unsigned d = s_dst[idx];
        if (d != 0xFFFFFFFFu) staging[d] = s_uv[idx];
    }
}

// --------- binacc: one block per bin; LDS atomic accumulate; dense coalesced A write ---------
__global__ void __launch_bounds__(256) k_binacc(
    const unsigned int* __restrict__ gcount, const uint2* __restrict__ staging,
    float* __restrict__ A, int Nx)
{
    __shared__ float Ab[BINW*ASTRIDE];   // 57344 B
    int t = threadIdx.x;
    int b = blockIdx.x;
    for (int i = t; i < BINW*ASTRIDE; i += 256) Ab[i] = 0.f;
    __syncthreads();

    unsigned n = gcount[b]; if (n > BCAP) n = BCAP;
    const uint2* sp = staging + (size_t)b*BCAP;
    for (unsigned idx = t; idx < n; idx += 256){
        uint2 ent = sp[idx];
        float att = __uint_as_float(ent.x);
        unsigned meta = ent.y;
        atomicAdd(&Ab[(meta >> 5)*ASTRIDE + (meta & 31u)], att);
    }
    __syncthreads();

    int j0 = b * BINW;
    int rows = min(BINW, Nx - j0);
    if (rows <= 0) return;
    const float4* srcp = (const float4*)Ab;
    float4* dstp = (float4*)(A + (size_t)j0*ASTRIDE);
    int n4 = rows * (ASTRIDE/4);
    for (int i = t; i < n4; i += 256) dstp[i] = srcp[i];
}

// --------- final: out[j,:] = x[j,:] * (b_inv + sum_k A[j][k] * W_inv[k,:]) ---------
__global__ void __launch_bounds__(256) k_final(
    const float* __restrict__ x, const float* __restrict__ A,
    const float* __restrict__ Winv, const float* __restrict__ binv,
    float* __restrict__ out, int Nx, int K)
{
    __shared__ float Wl[27*64];
    __shared__ float bl[64];
    __shared__ float Al[64*36];
    int t = threadIdx.x;
    for (int idx = t; idx < 27*64/4; idx += 256)
        ((float4*)Wl)[idx] = ((const float4*)Winv)[idx];
    if (t < 64) bl[t] = binv[t];
    int j0 = blockIdx.x * 64;
    for (int idx = t; idx < 64*(ASTRIDE/4); idx += 256){
        int r = idx / (ASTRIDE/4);
        int c4 = idx % (ASTRIDE/4);
        float4 v = make_float4(0.f,0.f,0.f,0.f);
        if (j0 + r < Nx) v = ld4(A + (size_t)(j0+r)*ASTRIDE + c4*4);
        st4(&Al[r*36 + c4*4], v);
    }
    __syncthreads();

    int cc = (t & 15) * 4;
    int jb = t >> 4;
    float4 acc[4];
    float4 b4 = ld4(&bl[cc]);
    #pragma unroll
    for (int q=0;q<4;q++) acc[q] = b4;
    for (int k=0;k<K;k++){
        float4 wv = ld4(&Wl[k*64 + cc]);
        #pragma unroll
        for (int q=0;q<4;q++){
            float a = Al[(q*16 + jb)*36 + k];
            acc[q].x = fmaf(a, wv.x, acc[q].x);
            acc[q].y = fmaf(a, wv.y, acc[q].y);
            acc[q].z = fmaf(a, wv.z, acc[q].z);
            acc[q].w = fmaf(a, wv.w, acc[q].w);
        }
    }
    #pragma unroll
    for (int q=0;q<4;q++){
        int j = j0 + q*16 + jb;
        if (j < Nx){
            float4 xv = ld4(x + (size_t)j*CS + cc);
            st4(out + (size_t)j*CS + cc,
                make_float4(xv.x*acc[q].x, xv.y*acc[q].y, xv.z*acc[q].z, xv.w*acc[q].w));
        }
    }
}

extern "C" void kernel_launch(void* const* d_in, const int* in_sizes, int n_in,
                              void* d_out, int out_size, void* d_ws, size_t ws_size,
                              hipStream_t stream)
{
    const float* g        = (const float*)d_in[0];
    const float* x        = (const float*)d_in[1];
    const int*   down_idx = (const int*)d_in[2];
    const int*   pin      = (const int*)d_in[3];
    const int*   pout     = (const int*)d_in[4];
    const float* Wg       = (const float*)d_in[5];
    const float* Ws       = (const float*)d_in[6];
    const float* Wc       = (const float*)d_in[7];
    const float* Winv     = (const float*)d_in[8];
    const float* binv     = (const float*)d_in[9];
    const float* gamma_g  = (const float*)d_in[10];
    const float* beta_g   = (const float*)d_in[11];
    const float* gamma_s  = (const float*)d_in[12];
    const float* beta_s   = (const float*)d_in[13];
    const float* gamma_c  = (const float*)d_in[14];
    const float* beta_c   = (const float*)d_in[15];

    int Ng = in_sizes[0] / CG;       // 60000
    int Nx = in_sizes[1] / CS;       // 200000
    int K  = in_sizes[8] / CS;       // 27
    int P  = in_sizes[3] / K;        // 100000
    int E  = K * P;                  // 2.7M
    int NB = (Nx + BINW - 1) >> BINSH; // 391 bins
    int RB = (E + ECH - 1) / ECH;      // 1319 route/hist blocks
    int fb = (Ng + FROWS - 1) / FROWS; // 938 fuse blocks

    float* ws = (float*)d_ws;
    size_t offA     = 0;                          // A: Nx*ASTRIDE
    size_t offStats = (size_t)Nx * ASTRIDE;
    size_t offScsh  = offStats + 512;             // 16
    size_t offGc    = offScsh + 16;               // gcount: 512
    size_t offWp    = offGc + 512;                // wpart: 2048
    size_t offYg    = offWp + 2048;
    size_t offYs    = offYg + (size_t)Ng*CN;
    size_t offW     = offYs + (size_t)Ng*CN;
    size_t offHR    = offW + (size_t)Ng;          // histR: RB*NB uint
    size_t offHT    = offHR + (size_t)RB*NB;      // histT: RB*NB uint
    size_t offOf    = offHT + (size_t)RB*NB;      // offs:  RB*NB uint

    float* A      = ws + offA;
    float* stats  = ws + offStats;
    float* scsh   = ws + offScsh;
    unsigned* gcount = (unsigned*)(ws + offGc);
    float* wpart  = ws + offWp;
    float* Yg     = ws + offYg;
    float* Ys     = ws + offYs;
    float* wbuf   = ws + offW;
    unsigned* histR = (unsigned*)(ws + offHR);
    unsigned* histT = (unsigned*)(ws + offHT);
    unsigned* offsb = (unsigned*)(ws + offOf);
    // staging aliases Yg/Ys (dead after k_fuse): NB*BCAP uint2 = 6.41M u32 <= 7.68M u32
    uint2* staging = (uint2*)(ws + offYg);

    // zero only the gemm-stats accumulators
    hipMemsetAsync(stats, 0, 512 * sizeof(float), stream);

    int gb = (Ng + 63) / 64;
    k_gemm<CG,false><<<gb, 256, 0, stream>>>(g, nullptr, Wg, Yg, stats+0, stats+64, Ng);
    k_gemm<CS,true ><<<gb, 256, 0, stream>>>(x, down_idx, Ws, Ys, stats+128, stats+192, Ng);
    k_fuse<<<fb, 256, 0, stream>>>(Yg, Ys, stats, gamma_g, beta_g,
                                   gamma_s, beta_s, Wc, wbuf, wpart, Ng);
    k_hist<<<RB, 256, 0, stream>>>(pout, histR, histT, E, NB, RB);
    k_offs<<<NB+1, 256, 0, stream>>>(histT, offsb, gcount, wpart, fb,
                                     gamma_c, beta_c, scsh, RB, NB, Ng);
    k_route<<<RB, 256, 0, stream>>>(pin, pout, wbuf, scsh, offsb, histR,
                                    staging, E, P, NB);
    k_binacc<<<NB, 256, 0, stream>>>(gcount, staging, A, Nx);
    k_final<<<(Nx+63)/64, 256, 0, stream>>>(x, A, Winv, binv, (float*)d_out, Nx, K);
}

// Round 4
// 310.748 us; speedup vs baseline: 1.0849x; 1.0849x over previous
//
#include <hip/hip_runtime.h>
#include <hip/hip_bf16.h>
#include <math.h>

#define CN 64
#define CG 128
#define CS 64
#define EPSV 1e-5f
#define ASTRIDE 28   // A row stride (27 taps + 1 pad, 16B-aligned)

#define BINW 512     // j-rows per bin
#define BINSH 9
#define BCAP 8192    // entry capacity per bin (avg ~6900, 15-sigma headroom)
#define ECH 2048     // entries per hist/route block (8 rounds x 256)

#define FROWS 64     // rows per k_fuse block

__device__ __forceinline__ float4 ld4(const float* p){ return *(const float4*)p; }
__device__ __forceinline__ void st4(float* p, float4 v){ *(float4*)p = v; }

// ---------------- front: gemm-g + gemm-x + hist fused into one grid ----------------
// blocks [0,GB): Yg = g @ Wg; [GB,2GB): Ys = x[down] @ Ws; [2GB,2GB+RB): pout histogram.
// All three roles are independent -> co-resident latency hiding.
__global__ void __launch_bounds__(256) k_front(
    const float* __restrict__ g, const float* __restrict__ x,
    const int* __restrict__ down_idx,
    const float* __restrict__ Wg, const float* __restrict__ Ws,
    float* __restrict__ Yg, float* __restrict__ Ys, float* __restrict__ stats,
    const int* __restrict__ pout, unsigned* __restrict__ histR,
    unsigned* __restrict__ histT,
    int Ng, int E, int NB, int RB, int GB)
{
    __shared__ float smem[64*68 + 64*64];   // Xl(4352) + W panel(4096) = 33 KB
    int t = threadIdx.x;
    int bid = blockIdx.x;

    if (bid >= 2*GB){
        // ---- hist role ----
        unsigned* hist = (unsigned*)smem;
        for (int b = t; b < 512; b += 256) hist[b] = 0u;
        __syncthreads();
        int blk = bid - 2*GB;
        int e0 = blk * ECH;
        #pragma unroll
        for (int r = 0; r < ECH/256; ++r){
            int e = e0 + r*256 + t;
            if (e < E) atomicAdd(&hist[pout[e] >> BINSH], 1u);
        }
        __syncthreads();
        for (int b = t; b < NB; b += 256){
            unsigned h = hist[b];
            histR[(size_t)blk*NB + b] = h;
            histT[(size_t)b*RB + blk] = h;
        }
        return;
    }

    // ---- gemm role ----
    bool isG = bid < GB;
    int blk = isG ? bid : bid - GB;
    const float* X = isG ? g : x;
    const float* W = isG ? Wg : Ws;
    float* Y = isG ? Yg : Ys;
    float* sum   = isG ? stats : stats + 128;
    float* sumsq = sum + 64;
    int CK = isG ? CG : CS;

    float* Xl = smem;            // stride 68
    float* Wp = smem + 64*68;    // 64x64 panel

    int row0 = blk * 64;
    int cg = t & 15, rg = t >> 4;
    int c0 = cg*4, r0 = rg*4;
    float4 acc[4];
    #pragma unroll
    for (int rr=0;rr<4;rr++) acc[rr] = make_float4(0.f,0.f,0.f,0.f);

    for (int kc = 0; kc < CK; kc += 64){
        for (int idx = t; idx < 64*16; idx += 256){
            int r = idx >> 4;
            int c4 = idx & 15;
            float4 v = make_float4(0.f,0.f,0.f,0.f);
            int row = row0 + r;
            if (row < Ng){
                int src = isG ? row : down_idx[row];
                v = ((const float4*)(X + (size_t)src*CK + kc))[c4];
            }
            *(float4*)&Xl[r*68 + c4*4] = v;
        }
        // stage W panel rows kc..kc+63 (contiguous)
        for (int idx = t; idx < 64*64/4; idx += 256)
            ((float4*)Wp)[idx] = ((const float4*)(W + (size_t)kc*CN))[idx];
        __syncthreads();
        for (int k = 0; k < 64; k += 4){
            float4 w0 = ld4(&Wp[(k+0)*CN + c0]);
            float4 w1 = ld4(&Wp[(k+1)*CN + c0]);
            float4 w2 = ld4(&Wp[(k+2)*CN + c0]);
            float4 w3 = ld4(&Wp[(k+3)*CN + c0]);
            #pragma unroll
            for (int rr=0;rr<4;rr++){
                float4 xv = ld4(&Xl[(r0+rr)*68 + k]);
                acc[rr].x = fmaf(xv.x,w0.x, fmaf(xv.y,w1.x, fmaf(xv.z,w2.x, fmaf(xv.w,w3.x, acc[rr].x))));
                acc[rr].y = fmaf(xv.x,w0.y, fmaf(xv.y,w1.y, fmaf(xv.z,w2.y, fmaf(xv.w,w3.y, acc[rr].y))));
                acc[rr].z = fmaf(xv.x,w0.z, fmaf(xv.y,w1.z, fmaf(xv.z,w2.z, fmaf(xv.w,w3.z, acc[rr].z))));
                acc[rr].w = fmaf(xv.x,w0.w, fmaf(xv.y,w1.w, fmaf(xv.z,w2.w, fmaf(xv.w,w3.w, acc[rr].w))));
            }
        }
        __syncthreads();
    }

    float4 s4 = make_float4(0.f,0.f,0.f,0.f), q4 = make_float4(0.f,0.f,0.f,0.f);
    #pragma unroll
    for (int rr=0;rr<4;rr++){
        int row = row0 + r0 + rr;
        if (row < Ng) st4(Y + (size_t)row*CN + c0, acc[rr]);
        s4.x += acc[rr].x; s4.y += acc[rr].y; s4.z += acc[rr].z; s4.w += acc[rr].w;
        q4.x += acc[rr].x*acc[rr].x; q4.y += acc[rr].y*acc[rr].y;
        q4.z += acc[rr].z*acc[rr].z; q4.w += acc[rr].w*acc[rr].w;
    }
    float* red = Xl;
    __syncthreads();
    st4(red + rg*64 + c0, s4);
    st4(red + 1024 + rg*64 + c0, q4);
    __syncthreads();
    if (t < 64){
        float ss = 0.f, qq = 0.f;
        #pragma unroll
        for (int r=0;r<16;r++){ ss += red[r*64 + t]; qq += red[1024 + r*64 + t]; }
        atomicAdd(&sum[t], ss); atomicAdd(&sumsq[t], qq);
    }
}

__device__ __forceinline__ void bnparams(float4 s, float4 q, float4 gam, float4 bet,
                                         float invN, float4& scl, float4& sft)
{
    float mux = s.x*invN, muy = s.y*invN, muz = s.z*invN, muw = s.w*invN;
    float vx = q.x*invN - mux*mux, vy = q.y*invN - muy*muy;
    float vz = q.z*invN - muz*muz, vw = q.w*invN - muw*muw;
    scl = make_float4(gam.x*rsqrtf(vx+EPSV), gam.y*rsqrtf(vy+EPSV),
                      gam.z*rsqrtf(vz+EPSV), gam.w*rsqrtf(vw+EPSV));
    sft = make_float4(bet.x - mux*scl.x, bet.y - muy*scl.y,
                      bet.z - muz*scl.z, bet.w - muw*scl.w);
}

// --------- fuse: w[i] = relu(relu(BN(Yg)) + relu(BN(Ys))) @ Wc; per-block partial sum/sumsq ---------
__global__ void __launch_bounds__(256) k_fuse(
    const float* __restrict__ Yg, const float* __restrict__ Ys,
    const float* __restrict__ stats,
    const float* __restrict__ gamma_g, const float* __restrict__ beta_g,
    const float* __restrict__ gamma_s, const float* __restrict__ beta_s,
    const float* __restrict__ Wc,
    float* __restrict__ w, float* __restrict__ wpart, int Ng)
{
    int t = threadIdx.x; int l = t & 15; int r = t >> 4;
    int c4 = l*4;
    float invN = 1.0f/(float)Ng;
    float4 sclg, sftg, scls, sfts;
    bnparams(ld4(stats + c4),       ld4(stats + 64 + c4),  ld4(gamma_g + c4), ld4(beta_g + c4), invN, sclg, sftg);
    bnparams(ld4(stats + 128 + c4), ld4(stats + 192 + c4), ld4(gamma_s + c4), ld4(beta_s + c4), invN, scls, sfts);
    float4 wc = ld4(Wc + c4);

    int base = blockIdx.x * FROWS;
    float s_acc = 0.f, q_acc = 0.f;
    #pragma unroll
    for (int rr = 0; rr < FROWS/16; ++rr){
        int i = base + rr*16 + r;
        float partial = 0.f;
        if (i < Ng){
            float4 a = ld4(Yg + (size_t)i*CN + c4);
            float4 b = ld4(Ys + (size_t)i*CN + c4);
            float ax = fmaxf(0.f, fmaf(a.x, sclg.x, sftg.x));
            float ay = fmaxf(0.f, fmaf(a.y, sclg.y, sftg.y));
            float az = fmaxf(0.f, fmaf(a.z, sclg.z, sftg.z));
            float aw = fmaxf(0.f, fmaf(a.w, sclg.w, sftg.w));
            float bx = fmaxf(0.f, fmaf(b.x, scls.x, sfts.x));
            float by = fmaxf(0.f, fmaf(b.y, scls.y, sfts.y));
            float bz = fmaxf(0.f, fmaf(b.z, scls.z, sfts.z));
            float bw = fmaxf(0.f, fmaf(b.w, scls.w, sfts.w));
            float sx = fmaxf(0.f, ax+bx), sy = fmaxf(0.f, ay+by);
            float sz = fmaxf(0.f, az+bz), sw = fmaxf(0.f, aw+bw);
            partial = sx*wc.x + sy*wc.y + sz*wc.z + sw*wc.w;
        }
        partial += __shfl_xor(partial, 1);
        partial += __shfl_xor(partial, 2);
        partial += __shfl_xor(partial, 4);
        partial += __shfl_xor(partial, 8);
        if (l == 0){
            if (i < Ng) w[i] = partial;
            s_acc += partial;
            q_acc += partial*partial;
        }
    }
    __shared__ float red[32];
    if (l == 0){ red[r] = s_acc; red[16+r] = q_acc; }
    __syncthreads();
    if (t == 0){
        float s2=0.f,q2=0.f;
        #pragma unroll
        for (int j2=0;j2<16;j2++){ s2+=red[j2]; q2+=red[16+j2]; }
        wpart[2*blockIdx.x]   = s2;
        wpart[2*blockIdx.x+1] = q2;
    }
}

// --------- offs: per-bin exclusive prefix over blocks (deterministic staging offsets, NO atomics) ---------
// block b < NB: scan histT[b][*] -> offs[blk][b]; gcount[b]=total.  block NB: wpart -> BN scale/shift.
__global__ void __launch_bounds__(256) k_offs(
    const unsigned* __restrict__ histT, unsigned* __restrict__ offs,
    unsigned* __restrict__ gcount,
    const float* __restrict__ wpart, int nf,
    const float* __restrict__ gamma_c, const float* __restrict__ beta_c,
    float* __restrict__ scsh, int RB, int NB, int Ng)
{
    int t = threadIdx.x;
    int b = blockIdx.x;
    if (b == NB){
        __shared__ float r8[8];
        float ls = 0.f, lq = 0.f;
        for (int i = t; i < nf; i += 256){ ls += wpart[2*i]; lq += wpart[2*i+1]; }
        #pragma unroll
        for (int off = 1; off < 64; off <<= 1){
            ls += __shfl_xor(ls, off);
            lq += __shfl_xor(lq, off);
        }
        if ((t & 63) == 0){ r8[t>>6] = ls; r8[4 + (t>>6)] = lq; }
        __syncthreads();
        if (t == 0){
            float S = r8[0]+r8[1]+r8[2]+r8[3];
            float Q = r8[4]+r8[5]+r8[6]+r8[7];
            float invN = 1.0f/(float)Ng;
            float mu = S*invN;
            float var = Q*invN - mu*mu;
            float sc = gamma_c[0]*rsqrtf(var+EPSV);
            scsh[0] = sc;
            scsh[1] = beta_c[0] - mu*sc;
        }
        return;
    }
    // RB <= 2048 assumed (E=2.7M, ECH=2048 -> RB=1319)
    __shared__ unsigned sv[2048];
    __shared__ unsigned pA[256];
    __shared__ unsigned pB[256];
    const unsigned* col = histT + (size_t)b*RB;
    for (int i = t; i < RB; i += 256) sv[i] = col[i];
    __syncthreads();
    int chunk = (RB + 255) / 256;
    int i0 = t*chunk;
    unsigned s = 0u;
    for (int c = 0; c < chunk; ++c){ int i = i0 + c; if (i < RB) s += sv[i]; }
    pA[t] = s;
    __syncthreads();
    unsigned* srcp = pA; unsigned* dstp = pB;
    for (int off = 1; off < 256; off <<= 1){
        unsigned v = srcp[t];
        if (t >= off) v += srcp[t-off];
        dstp[t] = v;
        __syncthreads();
        unsigned* tmp = srcp; srcp = dstp; dstp = tmp;
    }
    unsigned run = (t == 0) ? 0u : srcp[t-1];
    for (int c = 0; c < chunk; ++c){
        int i = i0 + c;
        if (i < RB){ offs[(size_t)i*NB + b] = run; run += sv[i]; }
    }
    if (t == 255) gcount[b] = srcp[255];
}

// --------- route: deterministic binned scatter of PACKED u32 entries (i:16 | k:5 | localj:9) ---------
// Zero global atomics; no w/sigmoid here (moved to binacc). Halved staging traffic.
__global__ void __launch_bounds__(256) k_route(
    const int* __restrict__ pin, const int* __restrict__ pout,
    const unsigned* __restrict__ offs, const unsigned* __restrict__ histR,
    unsigned* __restrict__ staging, int E, int P, int NB)
{
    __shared__ unsigned hist[512];
    __shared__ unsigned gbase[512];
    __shared__ unsigned lbase[512];
    __shared__ unsigned rank2[512];
    __shared__ unsigned scn[2][512];
    __shared__ unsigned s_dst[ECH];
    __shared__ unsigned s_u[ECH];

    int t = threadIdx.x, blk = blockIdx.x;
    for (int b = t; b < 512; b += 256){
        unsigned h = (b < NB) ? histR[(size_t)blk*NB + b] : 0u;
        hist[b] = h; scn[0][b] = h; rank2[b] = 0u;
        gbase[b] = (b < NB) ? offs[(size_t)blk*NB + b] : 0u;
    }
    __syncthreads();

    int src = 0;
    for (int off = 1; off < 512; off <<= 1){
        for (int i = t; i < 512; i += 256){
            unsigned v = scn[src][i];
            if (i >= off) v += scn[src][i-off];
            scn[src^1][i] = v;
        }
        __syncthreads();
        src ^= 1;
    }
    for (int b = t; b < 512; b += 256) lbase[b] = scn[src][b] - hist[b];

    int e0 = blk * ECH;
    int k0 = e0 / P;                 // one divide per thread (ECH < P)
    int rem0 = e0 - k0*P;
    __syncthreads();

    // pass B: assign deterministic slots, pack (i,k,localj) into 32 bits
    #pragma unroll
    for (int r = 0; r < ECH/256; ++r){
        int L = r*256 + t;
        int e = e0 + L;
        if (e < E){
            int j = pout[e];
            int i = pin[e];
            int b = j >> BINSH;
            int k = k0 + ((rem0 + L >= P) ? 1 : 0);
            unsigned rk = atomicAdd(&rank2[b], 1u);
            unsigned slot = lbase[b] + rk;
            unsigned d = gbase[b] + rk;
            if (d < BCAP){
                s_u[slot] = ((unsigned)(j & (BINW-1)) << 21) |
                            ((unsigned)k << 16) | (unsigned)i;
                s_dst[slot] = (unsigned)b*BCAP + d;
            } else {
                s_dst[slot] = 0xFFFFFFFFu;   // statistically impossible overflow: drop
            }
        }
    }
    __syncthreads();

    // pass C: pure coalesced flush of bin-ordered runs
    int nval = min(ECH, E - e0);
    for (int idx = t; idx < nval; idx += 256){
        unsigned d = s_dst[idx];
        if (d != 0xFFFFFFFFu) staging[d] = s_u[idx];
    }
}

// --------- binacc: one block per bin; att = sigmoid(BN(w[i])) fused with LDS accumulate ---------
__global__ void __launch_bounds__(256) k_binacc(
    const unsigned* __restrict__ gcount, const unsigned* __restrict__ staging,
    const float* __restrict__ w, const float* __restrict__ scsh,
    float* __restrict__ A, int Nx)
{
    __shared__ float Ab[BINW*ASTRIDE];   // 57344 B
    int t = threadIdx.x;
    int b = blockIdx.x;
    for (int i = t; i < BINW*ASTRIDE; i += 256) Ab[i] = 0.f;
    __syncthreads();

    float sc = scsh[0], sh = scsh[1];
    unsigned n = gcount[b]; if (n > BCAP) n = BCAP;
    const unsigned* sp = staging + (size_t)b*BCAP;
    unsigned n4 = n & ~3u;
    for (unsigned base = 4u*(unsigned)t; base < n4; base += 1024u){
        uint4 e4 = *(const uint4*)(sp + base);
        float w0 = w[e4.x & 0xFFFFu];
        float w1 = w[e4.y & 0xFFFFu];
        float w2 = w[e4.z & 0xFFFFu];
        float w3 = w[e4.w & 0xFFFFu];
        float a0 = 1.0f/(1.0f+__expf(-fmaf(sc, w0, sh)));
        float a1 = 1.0f/(1.0f+__expf(-fmaf(sc, w1, sh)));
        float a2 = 1.0f/(1.0f+__expf(-fmaf(sc, w2, sh)));
        float a3 = 1.0f/(1.0f+__expf(-fmaf(sc, w3, sh)));
        atomicAdd(&Ab[(e4.x >> 21)*ASTRIDE + ((e4.x >> 16) & 31u)], a0);
        atomicAdd(&Ab[(e4.y >> 21)*ASTRIDE + ((e4.y >> 16) & 31u)], a1);
        atomicAdd(&Ab[(e4.z >> 21)*ASTRIDE + ((e4.z >> 16) & 31u)], a2);
        atomicAdd(&Ab[(e4.w >> 21)*ASTRIDE + ((e4.w >> 16) & 31u)], a3);
    }
    for (unsigned idx = n4 + t; idx < n; idx += 256){
        unsigned e = sp[idx];
        float att = 1.0f/(1.0f+__expf(-fmaf(sc, w[e & 0xFFFFu], sh)));
        atomicAdd(&Ab[(e >> 21)*ASTRIDE + ((e >> 16) & 31u)], att);
    }
    __syncthreads();

    int j0 = b * BINW;
    int rows = min(BINW, Nx - j0);
    if (rows <= 0) return;
    const float4* srcp = (const float4*)Ab;
    float4* dstp = (float4*)(A + (size_t)j0*ASTRIDE);
    int nq = rows * (ASTRIDE/4);
    for (int i = t; i < nq; i += 256) dstp[i] = srcp[i];
}

// --------- final: out[j,:] = x[j,:] * (b_inv + sum_k A[j][k] * W_inv[k,:]) ---------
__global__ void __launch_bounds__(256) k_final(
    const float* __restrict__ x, const float* __restrict__ A,
    const float* __restrict__ Winv, const float* __restrict__ binv,
    float* __restrict__ out, int Nx, int K)
{
    __shared__ float Wl[27*64];
    __shared__ float bl[64];
    __shared__ float Al[64*36];
    int t = threadIdx.x;
    for (int idx = t; idx < 27*64/4; idx += 256)
        ((float4*)Wl)[idx] = ((const float4*)Winv)[idx];
    if (t < 64) bl[t] = binv[t];
    int j0 = blockIdx.x * 64;
    for (int idx = t; idx < 64*(ASTRIDE/4); idx += 256){
        int r = idx / (ASTRIDE/4);
        int c4 = idx % (ASTRIDE/4);
        float4 v = make_float4(0.f,0.f,0.f,0.f);
        if (j0 + r < Nx) v = ld4(A + (size_t)(j0+r)*ASTRIDE + c4*4);
        st4(&Al[r*36 + c4*4], v);
    }
    __syncthreads();

    int cc = (t & 15) * 4;
    int jb = t >> 4;
    float4 acc[4];
    float4 b4 = ld4(&bl[cc]);
    #pragma unroll
    for (int q=0;q<4;q++) acc[q] = b4;
    for (int k=0;k<K;k++){
        float4 wv = ld4(&Wl[k*64 + cc]);
        #pragma unroll
        for (int q=0;q<4;q++){
            float a = Al[(q*16 + jb)*36 + k];
            acc[q].x = fmaf(a, wv.x, acc[q].x);
            acc[q].y = fmaf(a, wv.y, acc[q].y);
            acc[q].z = fmaf(a, wv.z, acc[q].z);
            acc[q].w = fmaf(a, wv.w, acc[q].w);
        }
    }
    #pragma unroll
    for (int q=0;q<4;q++){
        int j = j0 + q*16 + jb;
        if (j < Nx){
            float4 xv = ld4(x + (size_t)j*CS + cc);
            st4(out + (size_t)j*CS + cc,
                make_float4(xv.x*acc[q].x, xv.y*acc[q].y, xv.z*acc[q].z, xv.w*acc[q].w));
        }
    }
}

extern "C" void kernel_launch(void* const* d_in, const int* in_sizes, int n_in,
                              void* d_out, int out_size, void* d_ws, size_t ws_size,
                              hipStream_t stream)
{
    const float* g        = (const float*)d_in[0];
    const float* x        = (const float*)d_in[1];
    const int*   down_idx = (const int*)d_in[2];
    const int*   pin      = (const int*)d_in[3];
    const int*   pout     = (const int*)d_in[4];
    const float* Wg       = (const float*)d_in[5];
    const float* Ws       = (const float*)d_in[6];
    const float* Wc       = (const float*)d_in[7];
    const float* Winv     = (const float*)d_in[8];
    const float* binv     = (const float*)d_in[9];
    const float* gamma_g  = (const float*)d_in[10];
    const float* beta_g   = (const float*)d_in[11];
    const float* gamma_s  = (const float*)d_in[12];
    const float* beta_s   = (const float*)d_in[13];
    const float* gamma_c  = (const float*)d_in[14];
    const float* beta_c   = (const float*)d_in[15];

    int Ng = in_sizes[0] / CG;       // 60000 (< 65536: packed-entry requirement)
    int Nx = in_sizes[1] / CS;       // 200000
    int K  = in_sizes[8] / CS;       // 27
    int P  = in_sizes[3] / K;        // 100000
    int E  = K * P;                  // 2.7M
    int NB = (Nx + BINW - 1) >> BINSH; // 391 bins
    int RB = (E + ECH - 1) / ECH;      // 1319 hist/route blocks
    int GB = (Ng + 63) / 64;           // 938 gemm blocks per branch
    int fb = (Ng + FROWS - 1) / FROWS; // 938 fuse blocks

    float* ws = (float*)d_ws;
    size_t offA     = 0;                          // A: Nx*ASTRIDE
    size_t offStats = (size_t)Nx * ASTRIDE;
    size_t offScsh  = offStats + 512;             // 16
    size_t offGc    = offScsh + 16;               // gcount: 512
    size_t offWp    = offGc + 512;                // wpart: 2048
    size_t offYg    = offWp + 2048;
    size_t offYs    = offYg + (size_t)Ng*CN;
    size_t offW     = offYs + (size_t)Ng*CN;
    size_t offHR    = offW + (size_t)Ng;          // histR: RB*NB uint
    size_t offHT    = offHR + (size_t)RB*NB;      // histT: RB*NB uint
    size_t offOf    = offHT + (size_t)RB*NB;      // offs:  RB*NB uint

    float* A      = ws + offA;
    float* stats  = ws + offStats;
    float* scsh   = ws + offScsh;
    unsigned* gcount = (unsigned*)(ws + offGc);
    float* wpart  = ws + offWp;
    float* Yg     = ws + offYg;
    float* Ys     = ws + offYs;
    float* wbuf   = ws + offW;
    unsigned* histR = (unsigned*)(ws + offHR);
    unsigned* histT = (unsigned*)(ws + offHT);
    unsigned* offsb = (unsigned*)(ws + offOf);
    // staging aliases Yg (dead after k_fuse): NB*BCAP u32 = 3.2M u32 <= Ng*CN = 3.84M floats
    unsigned* staging = (unsigned*)(ws + offYg);

    // zero only the gemm-stats accumulators
    hipMemsetAsync(stats, 0, 512 * sizeof(float), stream);

    k_front<<<2*GB + RB, 256, 0, stream>>>(g, x, down_idx, Wg, Ws, Yg, Ys, stats,
                                           pout, histR, histT, Ng, E, NB, RB, GB);
    k_fuse<<<fb, 256, 0, stream>>>(Yg, Ys, stats, gamma_g, beta_g,
                                   gamma_s, beta_s, Wc, wbuf, wpart, Ng);
    k_offs<<<NB+1, 256, 0, stream>>>(histT, offsb, gcount, wpart, fb,
                                     gamma_c, beta_c, scsh, RB, NB, Ng);
    k_route<<<RB, 256, 0, stream>>>(pin, pout, offsb, histR, staging, E, P, NB);
    k_binacc<<<NB, 256, 0, stream>>>(gcount, staging, wbuf, scsh, A, Nx);
    k_final<<<(Nx+63)/64, 256, 0, stream>>>(x, A, Winv, binv, (float*)d_out, Nx, K);
}

// Round 5
// 309.933 us; speedup vs baseline: 1.0877x; 1.0026x over previous
//
#include <hip/hip_runtime.h>
#include <hip/hip_bf16.h>
#include <math.h>

#define CN 64
#define CG 128
#define CS 64
#define EPSV 1e-5f
#define ASTRIDE 28   // Ab row stride in LDS (27 taps + 1 pad)

#define BINW 512     // j-rows per bin
#define BINSH 9
#define BCAP 8192    // entry capacity per bin (avg ~6900, 15-sigma headroom)
#define ECH 2048     // entries per hist/route block (8 rounds x 256)

#define FROWS 64     // rows per k_fuse block

__device__ __forceinline__ float4 ld4(const float* p){ return *(const float4*)p; }
__device__ __forceinline__ void st4(float* p, float4 v){ *(float4*)p = v; }

// ---------------- front: gemm-g + gemm-x + hist fused into one grid ----------------
// blocks [0,GB): Yg = g @ Wg; [GB,2GB): Ys = x[down] @ Ws; [2GB,2GB+RB): pout histogram.
// W read straight from global (L1/L2-resident, coalesced broadcast) -> LDS = 17.4 KB
// -> ~7 blocks/CU residency (VGPR-capped), vs 4 with the W panel staged.
__global__ void __launch_bounds__(256) k_front(
    const float* __restrict__ g, const float* __restrict__ x,
    const int* __restrict__ down_idx,
    const float* __restrict__ Wg, const float* __restrict__ Ws,
    float* __restrict__ Yg, float* __restrict__ Ys, float* __restrict__ stats,
    const int* __restrict__ pout, unsigned* __restrict__ histR,
    unsigned* __restrict__ histT,
    int Ng, int E, int NB, int RB, int GB)
{
    __shared__ float smem[64*68];   // Xl only: 17.4 KB
    int t = threadIdx.x;
    int bid = blockIdx.x;

    if (bid >= 2*GB){
        // ---- hist role ----
        unsigned* hist = (unsigned*)smem;
        for (int b = t; b < 512; b += 256) hist[b] = 0u;
        __syncthreads();
        int blk = bid - 2*GB;
        int e0 = blk * ECH;
        #pragma unroll
        for (int r = 0; r < ECH/256; ++r){
            int e = e0 + r*256 + t;
            if (e < E) atomicAdd(&hist[pout[e] >> BINSH], 1u);
        }
        __syncthreads();
        for (int b = t; b < NB; b += 256){
            unsigned h = hist[b];
            histR[(size_t)blk*NB + b] = h;
            histT[(size_t)b*RB + blk] = h;
        }
        return;
    }

    // ---- gemm role ----
    bool isG = bid < GB;
    int blk = isG ? bid : bid - GB;
    const float* X = isG ? g : x;
    const float* W = isG ? Wg : Ws;
    float* Y = isG ? Yg : Ys;
    float* sum   = isG ? stats : stats + 128;
    float* sumsq = sum + 64;
    int CK = isG ? CG : CS;

    float* Xl = smem;            // stride 68

    int row0 = blk * 64;
    int cg = t & 15, rg = t >> 4;
    int c0 = cg*4, r0 = rg*4;
    float4 acc[4];
    #pragma unroll
    for (int rr=0;rr<4;rr++) acc[rr] = make_float4(0.f,0.f,0.f,0.f);

    for (int kc = 0; kc < CK; kc += 64){
        for (int idx = t; idx < 64*16; idx += 256){
            int r = idx >> 4;
            int c4 = idx & 15;
            float4 v = make_float4(0.f,0.f,0.f,0.f);
            int row = row0 + r;
            if (row < Ng){
                int src = isG ? row : down_idx[row];
                v = ((const float4*)(X + (size_t)src*CK + kc))[c4];
            }
            *(float4*)&Xl[r*68 + c4*4] = v;
        }
        __syncthreads();
        const float* Wk = W + (size_t)kc*CN;
        for (int k = 0; k < 64; k += 4){
            float4 w0 = ld4(Wk + (k+0)*CN + c0);
            float4 w1 = ld4(Wk + (k+1)*CN + c0);
            float4 w2 = ld4(Wk + (k+2)*CN + c0);
            float4 w3 = ld4(Wk + (k+3)*CN + c0);
            #pragma unroll
            for (int rr=0;rr<4;rr++){
                float4 xv = ld4(&Xl[(r0+rr)*68 + k]);
                acc[rr].x = fmaf(xv.x,w0.x, fmaf(xv.y,w1.x, fmaf(xv.z,w2.x, fmaf(xv.w,w3.x, acc[rr].x))));
                acc[rr].y = fmaf(xv.x,w0.y, fmaf(xv.y,w1.y, fmaf(xv.z,w2.y, fmaf(xv.w,w3.y, acc[rr].y))));
                acc[rr].z = fmaf(xv.x,w0.z, fmaf(xv.y,w1.z, fmaf(xv.z,w2.z, fmaf(xv.w,w3.z, acc[rr].z))));
                acc[rr].w = fmaf(xv.x,w0.w, fmaf(xv.y,w1.w, fmaf(xv.z,w2.w, fmaf(xv.w,w3.w, acc[rr].w))));
            }
        }
        __syncthreads();
    }

    float4 s4 = make_float4(0.f,0.f,0.f,0.f), q4 = make_float4(0.f,0.f,0.f,0.f);
    #pragma unroll
    for (int rr=0;rr<4;rr++){
        int row = row0 + r0 + rr;
        if (row < Ng) st4(Y + (size_t)row*CN + c0, acc[rr]);
        s4.x += acc[rr].x; s4.y += acc[rr].y; s4.z += acc[rr].z; s4.w += acc[rr].w;
        q4.x += acc[rr].x*acc[rr].x; q4.y += acc[rr].y*acc[rr].y;
        q4.z += acc[rr].z*acc[rr].z; q4.w += acc[rr].w*acc[rr].w;
    }
    float* red = Xl;
    __syncthreads();
    st4(red + rg*64 + c0, s4);
    st4(red + 1024 + rg*64 + c0, q4);
    __syncthreads();
    if (t < 64){
        float ss = 0.f, qq = 0.f;
        #pragma unroll
        for (int r=0;r<16;r++){ ss += red[r*64 + t]; qq += red[1024 + r*64 + t]; }
        atomicAdd(&sum[t], ss); atomicAdd(&sumsq[t], qq);
    }
}

__device__ __forceinline__ void bnparams(float4 s, float4 q, float4 gam, float4 bet,
                                         float invN, float4& scl, float4& sft)
{
    float mux = s.x*invN, muy = s.y*invN, muz = s.z*invN, muw = s.w*invN;
    float vx = q.x*invN - mux*mux, vy = q.y*invN - muy*muy;
    float vz = q.z*invN - muz*muz, vw = q.w*invN - muw*muw;
    scl = make_float4(gam.x*rsqrtf(vx+EPSV), gam.y*rsqrtf(vy+EPSV),
                      gam.z*rsqrtf(vz+EPSV), gam.w*rsqrtf(vw+EPSV));
    sft = make_float4(bet.x - mux*scl.x, bet.y - muy*scl.y,
                      bet.z - muz*scl.z, bet.w - muw*scl.w);
}

// --------- fuse: w[i] = relu(relu(BN(Yg)) + relu(BN(Ys))) @ Wc; per-block partial sum/sumsq ---------
__global__ void __launch_bounds__(256) k_fuse(
    const float* __restrict__ Yg, const float* __restrict__ Ys,
    const float* __restrict__ stats,
    const float* __restrict__ gamma_g, const float* __restrict__ beta_g,
    const float* __restrict__ gamma_s, const float* __restrict__ beta_s,
    const float* __restrict__ Wc,
    float* __restrict__ w, float* __restrict__ wpart, int Ng)
{
    int t = threadIdx.x; int l = t & 15; int r = t >> 4;
    int c4 = l*4;
    float invN = 1.0f/(float)Ng;
    float4 sclg, sftg, scls, sfts;
    bnparams(ld4(stats + c4),       ld4(stats + 64 + c4),  ld4(gamma_g + c4), ld4(beta_g + c4), invN, sclg, sftg);
    bnparams(ld4(stats + 128 + c4), ld4(stats + 192 + c4), ld4(gamma_s + c4), ld4(beta_s + c4), invN, scls, sfts);
    float4 wc = ld4(Wc + c4);

    int base = blockIdx.x * FROWS;
    float s_acc = 0.f, q_acc = 0.f;
    #pragma unroll
    for (int rr = 0; rr < FROWS/16; ++rr){
        int i = base + rr*16 + r;
        float partial = 0.f;
        if (i < Ng){
            float4 a = ld4(Yg + (size_t)i*CN + c4);
            float4 b = ld4(Ys + (size_t)i*CN + c4);
            float ax = fmaxf(0.f, fmaf(a.x, sclg.x, sftg.x));
            float ay = fmaxf(0.f, fmaf(a.y, sclg.y, sftg.y));
            float az = fmaxf(0.f, fmaf(a.z, sclg.z, sftg.z));
            float aw = fmaxf(0.f, fmaf(a.w, sclg.w, sftg.w));
            float bx = fmaxf(0.f, fmaf(b.x, scls.x, sfts.x));
            float by = fmaxf(0.f, fmaf(b.y, scls.y, sfts.y));
            float bz = fmaxf(0.f, fmaf(b.z, scls.z, sfts.z));
            float bw = fmaxf(0.f, fmaf(b.w, scls.w, sfts.w));
            float sx = fmaxf(0.f, ax+bx), sy = fmaxf(0.f, ay+by);
            float sz = fmaxf(0.f, az+bz), sw = fmaxf(0.f, aw+bw);
            partial = sx*wc.x + sy*wc.y + sz*wc.z + sw*wc.w;
        }
        partial += __shfl_xor(partial, 1);
        partial += __shfl_xor(partial, 2);
        partial += __shfl_xor(partial, 4);
        partial += __shfl_xor(partial, 8);
        if (l == 0){
            if (i < Ng) w[i] = partial;
            s_acc += partial;
            q_acc += partial*partial;
        }
    }
    __shared__ float red[32];
    if (l == 0){ red[r] = s_acc; red[16+r] = q_acc; }
    __syncthreads();
    if (t == 0){
        float s2=0.f,q2=0.f;
        #pragma unroll
        for (int j2=0;j2<16;j2++){ s2+=red[j2]; q2+=red[16+j2]; }
        wpart[2*blockIdx.x]   = s2;
        wpart[2*blockIdx.x+1] = q2;
    }
}

// --------- offs: per-bin exclusive prefix over blocks (deterministic staging offsets, NO atomics) ---------
__global__ void __launch_bounds__(256) k_offs(
    const unsigned* __restrict__ histT, unsigned* __restrict__ offs,
    unsigned* __restrict__ gcount,
    const float* __restrict__ wpart, int nf,
    const float* __restrict__ gamma_c, const float* __restrict__ beta_c,
    float* __restrict__ scsh, int RB, int NB, int Ng)
{
    int t = threadIdx.x;
    int b = blockIdx.x;
    if (b == NB){
        __shared__ float r8[8];
        float ls = 0.f, lq = 0.f;
        for (int i = t; i < nf; i += 256){ ls += wpart[2*i]; lq += wpart[2*i+1]; }
        #pragma unroll
        for (int off = 1; off < 64; off <<= 1){
            ls += __shfl_xor(ls, off);
            lq += __shfl_xor(lq, off);
        }
        if ((t & 63) == 0){ r8[t>>6] = ls; r8[4 + (t>>6)] = lq; }
        __syncthreads();
        if (t == 0){
            float S = r8[0]+r8[1]+r8[2]+r8[3];
            float Q = r8[4]+r8[5]+r8[6]+r8[7];
            float invN = 1.0f/(float)Ng;
            float mu = S*invN;
            float var = Q*invN - mu*mu;
            float sc = gamma_c[0]*rsqrtf(var+EPSV);
            scsh[0] = sc;
            scsh[1] = beta_c[0] - mu*sc;
        }
        return;
    }
    // RB <= 2048 assumed (E=2.7M, ECH=2048 -> RB=1319)
    __shared__ unsigned sv[2048];
    __shared__ unsigned pA[256];
    __shared__ unsigned pB[256];
    const unsigned* col = histT + (size_t)b*RB;
    for (int i = t; i < RB; i += 256) sv[i] = col[i];
    __syncthreads();
    int chunk = (RB + 255) / 256;
    int i0 = t*chunk;
    unsigned s = 0u;
    for (int c = 0; c < chunk; ++c){ int i = i0 + c; if (i < RB) s += sv[i]; }
    pA[t] = s;
    __syncthreads();
    unsigned* srcp = pA; unsigned* dstp = pB;
    for (int off = 1; off < 256; off <<= 1){
        unsigned v = srcp[t];
        if (t >= off) v += srcp[t-off];
        dstp[t] = v;
        __syncthreads();
        unsigned* tmp = srcp; srcp = dstp; dstp = tmp;
    }
    unsigned run = (t == 0) ? 0u : srcp[t-1];
    for (int c = 0; c < chunk; ++c){
        int i = i0 + c;
        if (i < RB){ offs[(size_t)i*NB + b] = run; run += sv[i]; }
    }
    if (t == 255) gcount[b] = srcp[255];
}

// --------- route: deterministic binned scatter of PACKED u32 entries (localj:9 | k:5 | i:16) ---------
__global__ void __launch_bounds__(256) k_route(
    const int* __restrict__ pin, const int* __restrict__ pout,
    const unsigned* __restrict__ offs, const unsigned* __restrict__ histR,
    unsigned* __restrict__ staging, int E, int P, int NB)
{
    __shared__ unsigned hist[512];
    __shared__ unsigned gbase[512];
    __shared__ unsigned lbase[512];
    __shared__ unsigned rank2[512];
    __shared__ unsigned scn[2][512];
    __shared__ unsigned s_dst[ECH];
    __shared__ unsigned s_u[ECH];

    int t = threadIdx.x, blk = blockIdx.x;
    for (int b = t; b < 512; b += 256){
        unsigned h = (b < NB) ? histR[(size_t)blk*NB + b] : 0u;
        hist[b] = h; scn[0][b] = h; rank2[b] = 0u;
        gbase[b] = (b < NB) ? offs[(size_t)blk*NB + b] : 0u;
    }
    __syncthreads();

    int src = 0;
    for (int off = 1; off < 512; off <<= 1){
        for (int i = t; i < 512; i += 256){
            unsigned v = scn[src][i];
            if (i >= off) v += scn[src][i-off];
            scn[src^1][i] = v;
        }
        __syncthreads();
        src ^= 1;
    }
    for (int b = t; b < 512; b += 256) lbase[b] = scn[src][b] - hist[b];

    int e0 = blk * ECH;
    int k0 = e0 / P;                 // one divide per thread (ECH < P)
    int rem0 = e0 - k0*P;
    __syncthreads();

    // pass B: assign deterministic slots, pack (localj,k,i) into 32 bits
    #pragma unroll
    for (int r = 0; r < ECH/256; ++r){
        int L = r*256 + t;
        int e = e0 + L;
        if (e < E){
            int j = pout[e];
            int i = pin[e];
            int b = j >> BINSH;
            int k = k0 + ((rem0 + L >= P) ? 1 : 0);
            unsigned rk = atomicAdd(&rank2[b], 1u);
            unsigned slot = lbase[b] + rk;
            unsigned d = gbase[b] + rk;
            if (d < BCAP){
                s_u[slot] = ((unsigned)(j & (BINW-1)) << 21) |
                            ((unsigned)k << 16) | (unsigned)i;
                s_dst[slot] = (unsigned)b*BCAP + d;
            } else {
                s_dst[slot] = 0xFFFFFFFFu;   // statistically impossible overflow: drop
            }
        }
    }
    __syncthreads();

    // pass C: pure coalesced flush of bin-ordered runs
    int nval = min(ECH, E - e0);
    for (int idx = t; idx < nval; idx += 256){
        unsigned d = s_dst[idx];
        if (d != 0xFFFFFFFFu) staging[d] = s_u[idx];
    }
}

// --------- back: bin accumulate FUSED with the final gated product ---------
// One block per bin: Ab (512x28) accumulated in LDS via sigmoid(BN(w[i])) gathers,
// then out[j,:] = x[j,:] * (binv + Ab[j,:] @ Winv) directly -- A never touches HBM.
__global__ void __launch_bounds__(256) k_back(
    const unsigned* __restrict__ gcount, const unsigned* __restrict__ staging,
    const float* __restrict__ w, const float* __restrict__ scsh,
    const float* __restrict__ x, const float* __restrict__ Winv,
    const float* __restrict__ binv,
    float* __restrict__ out, int Nx, int K)
{
    __shared__ float Ab[BINW*ASTRIDE];   // 57344 B
    __shared__ float Wl[27*64];          // 6912 B [k][c]
    __shared__ float bl[64];
    int t = threadIdx.x;
    int b = blockIdx.x;
    for (int i = t; i < BINW*ASTRIDE/4; i += 256)
        ((float4*)Ab)[i] = make_float4(0.f,0.f,0.f,0.f);
    for (int idx = t; idx < 27*64/4; idx += 256)
        ((float4*)Wl)[idx] = ((const float4*)Winv)[idx];
    if (t < 64) bl[t] = binv[t];
    __syncthreads();

    float sc = scsh[0], sh = scsh[1];
    unsigned n = gcount[b]; if (n > BCAP) n = BCAP;
    const unsigned* sp = staging + (size_t)b*BCAP;
    unsigned n4 = n & ~3u;
    for (unsigned base = 4u*(unsigned)t; base < n4; base += 1024u){
        uint4 e4 = *(const uint4*)(sp + base);
        float w0 = w[e4.x & 0xFFFFu];
        float w1 = w[e4.y & 0xFFFFu];
        float w2 = w[e4.z & 0xFFFFu];
        float w3 = w[e4.w & 0xFFFFu];
        float a0 = 1.0f/(1.0f+__expf(-fmaf(sc, w0, sh)));
        float a1 = 1.0f/(1.0f+__expf(-fmaf(sc, w1, sh)));
        float a2 = 1.0f/(1.0f+__expf(-fmaf(sc, w2, sh)));
        float a3 = 1.0f/(1.0f+__expf(-fmaf(sc, w3, sh)));
        atomicAdd(&Ab[(e4.x >> 21)*ASTRIDE + ((e4.x >> 16) & 31u)], a0);
        atomicAdd(&Ab[(e4.y >> 21)*ASTRIDE + ((e4.y >> 16) & 31u)], a1);
        atomicAdd(&Ab[(e4.z >> 21)*ASTRIDE + ((e4.z >> 16) & 31u)], a2);
        atomicAdd(&Ab[(e4.w >> 21)*ASTRIDE + ((e4.w >> 16) & 31u)], a3);
    }
    for (unsigned idx = n4 + t; idx < n; idx += 256){
        unsigned e = sp[idx];
        float att = 1.0f/(1.0f+__expf(-fmaf(sc, w[e & 0xFFFFu], sh)));
        atomicAdd(&Ab[(e >> 21)*ASTRIDE + ((e >> 16) & 31u)], att);
    }
    __syncthreads();

    // final gated product for this bin's 512 rows (8 chunks of 64)
    int j0 = b * BINW;
    int cc = (t & 15) * 4;
    int jb = t >> 4;
    float4 b4 = ld4(&bl[cc]);
    for (int q0 = 0; q0 < BINW/64; ++q0){
        float4 acc[4];
        #pragma unroll
        for (int q=0;q<4;q++) acc[q] = b4;
        for (int k=0;k<K;k++){
            float4 wv = ld4(&Wl[k*64 + cc]);
            #pragma unroll
            for (int q=0;q<4;q++){
                float a = Ab[(q0*64 + q*16 + jb)*ASTRIDE + k];
                acc[q].x = fmaf(a, wv.x, acc[q].x);
                acc[q].y = fmaf(a, wv.y, acc[q].y);
                acc[q].z = fmaf(a, wv.z, acc[q].z);
                acc[q].w = fmaf(a, wv.w, acc[q].w);
            }
        }
        #pragma unroll
        for (int q=0;q<4;q++){
            int j = j0 + q0*64 + q*16 + jb;
            if (j < Nx){
                float4 xv = ld4(x + (size_t)j*CS + cc);
                st4(out + (size_t)j*CS + cc,
                    make_float4(xv.x*acc[q].x, xv.y*acc[q].y, xv.z*acc[q].z, xv.w*acc[q].w));
            }
        }
    }
}

extern "C" void kernel_launch(void* const* d_in, const int* in_sizes, int n_in,
                              void* d_out, int out_size, void* d_ws, size_t ws_size,
                              hipStream_t stream)
{
    const float* g        = (const float*)d_in[0];
    const float* x        = (const float*)d_in[1];
    const int*   down_idx = (const int*)d_in[2];
    const int*   pin      = (const int*)d_in[3];
    const int*   pout     = (const int*)d_in[4];
    const float* Wg       = (const float*)d_in[5];
    const float* Ws       = (const float*)d_in[6];
    const float* Wc       = (const float*)d_in[7];
    const float* Winv     = (const float*)d_in[8];
    const float* binv     = (const float*)d_in[9];
    const float* gamma_g  = (const float*)d_in[10];
    const float* beta_g   = (const float*)d_in[11];
    const float* gamma_s  = (const float*)d_in[12];
    const float* beta_s   = (const float*)d_in[13];
    const float* gamma_c  = (const float*)d_in[14];
    const float* beta_c   = (const float*)d_in[15];

    int Ng = in_sizes[0] / CG;       // 60000 (< 65536: packed-entry requirement)
    int Nx = in_sizes[1] / CS;       // 200000
    int K  = in_sizes[8] / CS;       // 27
    int P  = in_sizes[3] / K;        // 100000
    int E  = K * P;                  // 2.7M
    int NB = (Nx + BINW - 1) >> BINSH; // 391 bins
    int RB = (E + ECH - 1) / ECH;      // 1319 hist/route blocks
    int GB = (Ng + 63) / 64;           // 938 gemm blocks per branch
    int fb = (Ng + FROWS - 1) / FROWS; // 938 fuse blocks

    float* ws = (float*)d_ws;
    size_t offStats = 0;
    size_t offScsh  = offStats + 512;             // 16
    size_t offGc    = offScsh + 16;               // gcount: 512
    size_t offWp    = offGc + 512;                // wpart: 2048
    size_t offYg    = offWp + 2048;
    size_t offYs    = offYg + (size_t)Ng*CN;
    size_t offW     = offYs + (size_t)Ng*CN;
    size_t offHR    = offW + (size_t)Ng;          // histR: RB*NB uint
    size_t offHT    = offHR + (size_t)RB*NB;      // histT: RB*NB uint
    size_t offOf    = offHT + (size_t)RB*NB;      // offs:  RB*NB uint

    float* stats  = ws + offStats;
    float* scsh   = ws + offScsh;
    unsigned* gcount = (unsigned*)(ws + offGc);
    float* wpart  = ws + offWp;
    float* Yg     = ws + offYg;
    float* Ys     = ws + offYs;
    float* wbuf   = ws + offW;
    unsigned* histR = (unsigned*)(ws + offHR);
    unsigned* histT = (unsigned*)(ws + offHT);
    unsigned* offsb = (unsigned*)(ws + offOf);
    // staging aliases Yg (dead after k_fuse): NB*BCAP u32 = 3.2M u32 <= Ng*CN = 3.84M floats
    unsigned* staging = (unsigned*)(ws + offYg);

    // zero only the gemm-stats accumulators
    hipMemsetAsync(stats, 0, 512 * sizeof(float), stream);

    k_front<<<2*GB + RB, 256, 0, stream>>>(g, x, down_idx, Wg, Ws, Yg, Ys, stats,
                                           pout, histR, histT, Ng, E, NB, RB, GB);
    k_fuse<<<fb, 256, 0, stream>>>(Yg, Ys, stats, gamma_g, beta_g,
                                   gamma_s, beta_s, Wc, wbuf, wpart, Ng);
    k_offs<<<NB+1, 256, 0, stream>>>(histT, offsb, gcount, wpart, fb,
                                     gamma_c, beta_c, scsh, RB, NB, Ng);
    k_route<<<RB, 256, 0, stream>>>(pin, pout, offsb, histR, staging, E, P, NB);
    k_back<<<NB, 256, 0, stream>>>(gcount, staging, wbuf, scsh,
                                   x, Winv, binv, (float*)d_out, Nx, K);
}

// Round 7
// 278.006 us; speedup vs baseline: 1.2127x; 1.1148x over previous
//
#include <hip/hip_runtime.h>
#include <hip/hip_bf16.h>
#include <math.h>

#define CN 64
#define CG 128
#define CS 64
#define EPSV 1e-5f
#define ASTRIDE 28   // Ab row stride in LDS (27 taps + 1 pad)

#define BINW 512     // j-rows per staging bin
#define BINSH 9
#define BCAP 8192    // entry capacity per bin (avg ~6900, 15-sigma headroom)
#define ECH 2048     // entries per hist/route block (8 rounds x 256)

#define FROWS 64     // rows per k_fuse block
#define GROWS 128    // rows per gemm block (8 rows/thread)

__device__ __forceinline__ float4 ld4(const float* p){ return *(const float4*)p; }
__device__ __forceinline__ void st4(float* p, float4 v){ *(float4*)p = v; }

// ---------------- front: gemm-g + gemm-x + hist fused into one grid ----------------
// blocks [0,GB): Yg = g @ Wg; [GB,2GB): Ys = x[down] @ Ws; [2GB,2GB+RB): pout histogram.
// 8 rows/thread: 4 W loads cover 128 FMAs; W prefetched one k-step ahead in registers
// so the L1/L2 load latency is hidden inside a single wave.
__global__ void __launch_bounds__(256) k_front(
    const float* __restrict__ g, const float* __restrict__ x,
    const int* __restrict__ down_idx,
    const float* __restrict__ Wg, const float* __restrict__ Ws,
    float* __restrict__ Yg, float* __restrict__ Ys, float* __restrict__ stats,
    const int* __restrict__ pout, unsigned* __restrict__ histR,
    unsigned* __restrict__ histT,
    int Ng, int E, int NB, int RB, int GB)
{
    __shared__ float smem[GROWS*68];   // 34.8 KB
    int t = threadIdx.x;
    int bid = blockIdx.x;

    if (bid >= 2*GB){
        // ---- hist role ----
        unsigned* hist = (unsigned*)smem;
        for (int b = t; b < 512; b += 256) hist[b] = 0u;
        __syncthreads();
        int blk = bid - 2*GB;
        int e0 = blk * ECH;
        #pragma unroll
        for (int r = 0; r < ECH/256; ++r){
            int e = e0 + r*256 + t;
            if (e < E) atomicAdd(&hist[pout[e] >> BINSH], 1u);
        }
        __syncthreads();
        for (int b = t; b < NB; b += 256){
            unsigned h = hist[b];
            histR[(size_t)blk*NB + b] = h;
            histT[(size_t)b*RB + blk] = h;
        }
        return;
    }

    // ---- gemm role ----
    bool isG = bid < GB;
    int blk = isG ? bid : bid - GB;
    const float* X = isG ? g : x;
    const float* W = isG ? Wg : Ws;
    float* Y = isG ? Yg : Ys;
    float* sum   = isG ? stats : stats + 128;
    float* sumsq = sum + 64;
    int CK = isG ? CG : CS;

    float* Xl = smem;            // stride 68

    int row0 = blk * GROWS;
    int cg = t & 15, rg = t >> 4;
    int c0 = cg*4, r0 = rg*8;
    float4 acc[8];
    #pragma unroll
    for (int rr=0;rr<8;rr++) acc[rr] = make_float4(0.f,0.f,0.f,0.f);

    for (int kc = 0; kc < CK; kc += 64){
        for (int idx = t; idx < GROWS*16; idx += 256){
            int r = idx >> 4;
            int c4 = idx & 15;
            float4 v = make_float4(0.f,0.f,0.f,0.f);
            int row = row0 + r;
            if (row < Ng){
                int src = isG ? row : down_idx[row];
                v = ((const float4*)(X + (size_t)src*CK + kc))[c4];
            }
            *(float4*)&Xl[r*68 + c4*4] = v;
        }
        __syncthreads();
        const float* Wk = W + (size_t)kc*CN + c0;
        float4 w0 = ld4(Wk + 0*CN);
        float4 w1 = ld4(Wk + 1*CN);
        float4 w2 = ld4(Wk + 2*CN);
        float4 w3 = ld4(Wk + 3*CN);
        for (int k = 0; k < 64; k += 4){
            int kn = (k < 60) ? k + 4 : k;          // tail reload is dead
            float4 n0 = ld4(Wk + (kn+0)*CN);
            float4 n1 = ld4(Wk + (kn+1)*CN);
            float4 n2 = ld4(Wk + (kn+2)*CN);
            float4 n3 = ld4(Wk + (kn+3)*CN);
            #pragma unroll
            for (int rr=0;rr<8;rr++){
                float4 xv = ld4(&Xl[(r0+rr)*68 + k]);
                acc[rr].x = fmaf(xv.x,w0.x, fmaf(xv.y,w1.x, fmaf(xv.z,w2.x, fmaf(xv.w,w3.x, acc[rr].x))));
                acc[rr].y = fmaf(xv.x,w0.y, fmaf(xv.y,w1.y, fmaf(xv.z,w2.y, fmaf(xv.w,w3.y, acc[rr].y))));
                acc[rr].z = fmaf(xv.x,w0.z, fmaf(xv.y,w1.z, fmaf(xv.z,w2.z, fmaf(xv.w,w3.z, acc[rr].z))));
                acc[rr].w = fmaf(xv.x,w0.w, fmaf(xv.y,w1.w, fmaf(xv.z,w2.w, fmaf(xv.w,w3.w, acc[rr].w))));
            }
            w0 = n0; w1 = n1; w2 = n2; w3 = n3;
        }
        __syncthreads();
    }

    float4 s4 = make_float4(0.f,0.f,0.f,0.f), q4 = make_float4(0.f,0.f,0.f,0.f);
    #pragma unroll
    for (int rr=0;rr<8;rr++){
        int row = row0 + r0 + rr;
        if (row < Ng) st4(Y + (size_t)row*CN + c0, acc[rr]);
        s4.x += acc[rr].x; s4.y += acc[rr].y; s4.z += acc[rr].z; s4.w += acc[rr].w;
        q4.x += acc[rr].x*acc[rr].x; q4.y += acc[rr].y*acc[rr].y;
        q4.z += acc[rr].z*acc[rr].z; q4.w += acc[rr].w*acc[rr].w;
    }
    float* red = Xl;
    __syncthreads();
    st4(red + rg*64 + c0, s4);
    st4(red + 1024 + rg*64 + c0, q4);
    __syncthreads();
    if (t < 64){
        float ss = 0.f, qq = 0.f;
        #pragma unroll
        for (int r=0;r<16;r++){ ss += red[r*64 + t]; qq += red[1024 + r*64 + t]; }
        atomicAdd(&sum[t], ss); atomicAdd(&sumsq[t], qq);
    }
}

__device__ __forceinline__ void bnparams(float4 s, float4 q, float4 gam, float4 bet,
                                         float invN, float4& scl, float4& sft)
{
    float mux = s.x*invN, muy = s.y*invN, muz = s.z*invN, muw = s.w*invN;
    float vx = q.x*invN - mux*mux, vy = q.y*invN - muy*muy;
    float vz = q.z*invN - muz*muz, vw = q.w*invN - muw*muw;
    scl = make_float4(gam.x*rsqrtf(vx+EPSV), gam.y*rsqrtf(vy+EPSV),
                      gam.z*rsqrtf(vz+EPSV), gam.w*rsqrtf(vw+EPSV));
    sft = make_float4(bet.x - mux*scl.x, bet.y - muy*scl.y,
                      bet.z - muz*scl.z, bet.w - muw*scl.w);
}

// --------- fuse: w[i] = relu(relu(BN(Yg)) + relu(BN(Ys))) @ Wc; per-block partial sum/sumsq ---------
__global__ void __launch_bounds__(256) k_fuse(
    const float* __restrict__ Yg, const float* __restrict__ Ys,
    const float* __restrict__ stats,
    const float* __restrict__ gamma_g, const float* __restrict__ beta_g,
    const float* __restrict__ gamma_s, const float* __restrict__ beta_s,
    const float* __restrict__ Wc,
    float* __restrict__ w, float* __restrict__ wpart, int Ng)
{
    int t = threadIdx.x; int l = t & 15; int r = t >> 4;
    int c4 = l*4;
    float invN = 1.0f/(float)Ng;
    float4 sclg, sftg, scls, sfts;
    bnparams(ld4(stats + c4),       ld4(stats + 64 + c4),  ld4(gamma_g + c4), ld4(beta_g + c4), invN, sclg, sftg);
    bnparams(ld4(stats + 128 + c4), ld4(stats + 192 + c4), ld4(gamma_s + c4), ld4(beta_s + c4), invN, scls, sfts);
    float4 wc = ld4(Wc + c4);

    int base = blockIdx.x * FROWS;
    float s_acc = 0.f, q_acc = 0.f;
    #pragma unroll
    for (int rr = 0; rr < FROWS/16; ++rr){
        int i = base + rr*16 + r;
        float partial = 0.f;
        if (i < Ng){
            float4 a = ld4(Yg + (size_t)i*CN + c4);
            float4 b = ld4(Ys + (size_t)i*CN + c4);
            float ax = fmaxf(0.f, fmaf(a.x, sclg.x, sftg.x));
            float ay = fmaxf(0.f, fmaf(a.y, sclg.y, sftg.y));
            float az = fmaxf(0.f, fmaf(a.z, sclg.z, sftg.z));
            float aw = fmaxf(0.f, fmaf(a.w, sclg.w, sftg.w));
            float bx = fmaxf(0.f, fmaf(b.x, scls.x, sfts.x));
            float by = fmaxf(0.f, fmaf(b.y, scls.y, sfts.y));
            float bz = fmaxf(0.f, fmaf(b.z, scls.z, sfts.z));
            float bw = fmaxf(0.f, fmaf(b.w, scls.w, sfts.w));
            float sx = fmaxf(0.f, ax+bx), sy = fmaxf(0.f, ay+by);
            float sz = fmaxf(0.f, az+bz), sw = fmaxf(0.f, aw+bw);
            partial = sx*wc.x + sy*wc.y + sz*wc.z + sw*wc.w;
        }
        partial += __shfl_xor(partial, 1);
        partial += __shfl_xor(partial, 2);
        partial += __shfl_xor(partial, 4);
        partial += __shfl_xor(partial, 8);
        if (l == 0){
            if (i < Ng) w[i] = partial;
            s_acc += partial;
            q_acc += partial*partial;
        }
    }
    __shared__ float red[32];
    if (l == 0){ red[r] = s_acc; red[16+r] = q_acc; }
    __syncthreads();
    if (t == 0){
        float s2=0.f,q2=0.f;
        #pragma unroll
        for (int j2=0;j2<16;j2++){ s2+=red[j2]; q2+=red[16+j2]; }
        wpart[2*blockIdx.x]   = s2;
        wpart[2*blockIdx.x+1] = q2;
    }
}

// --------- offs: per-bin exclusive prefix over blocks (deterministic staging offsets, NO atomics) ---------
__global__ void __launch_bounds__(256) k_offs(
    const unsigned* __restrict__ histT, unsigned* __restrict__ offs,
    unsigned* __restrict__ gcount,
    const float* __restrict__ wpart, int nf,
    const float* __restrict__ gamma_c, const float* __restrict__ beta_c,
    float* __restrict__ scsh, int RB, int NB, int Ng)
{
    int t = threadIdx.x;
    int b = blockIdx.x;
    if (b == NB){
        __shared__ float r8[8];
        float ls = 0.f, lq = 0.f;
        for (int i = t; i < nf; i += 256){ ls += wpart[2*i]; lq += wpart[2*i+1]; }
        #pragma unroll
        for (int off = 1; off < 64; off <<= 1){
            ls += __shfl_xor(ls, off);
            lq += __shfl_xor(lq, off);
        }
        if ((t & 63) == 0){ r8[t>>6] = ls; r8[4 + (t>>6)] = lq; }
        __syncthreads();
        if (t == 0){
            float S = r8[0]+r8[1]+r8[2]+r8[3];
            float Q = r8[4]+r8[5]+r8[6]+r8[7];
            float invN = 1.0f/(float)Ng;
            float mu = S*invN;
            float var = Q*invN - mu*mu;
            float sc = gamma_c[0]*rsqrtf(var+EPSV);
            scsh[0] = sc;
            scsh[1] = beta_c[0] - mu*sc;
        }
        return;
    }
    // RB <= 2048 assumed (E=2.7M, ECH=2048 -> RB=1319)
    __shared__ unsigned sv[2048];
    __shared__ unsigned pA[256];
    __shared__ unsigned pB[256];
    const unsigned* col = histT + (size_t)b*RB;
    for (int i = t; i < RB; i += 256) sv[i] = col[i];
    __syncthreads();
    int chunk = (RB + 255) / 256;
    int i0 = t*chunk;
    unsigned s = 0u;
    for (int c = 0; c < chunk; ++c){ int i = i0 + c; if (i < RB) s += sv[i]; }
    pA[t] = s;
    __syncthreads();
    unsigned* srcp = pA; unsigned* dstp = pB;
    for (int off = 1; off < 256; off <<= 1){
        unsigned v = srcp[t];
        if (t >= off) v += srcp[t-off];
        dstp[t] = v;
        __syncthreads();
        unsigned* tmp = srcp; srcp = dstp; dstp = tmp;
    }
    unsigned run = (t == 0) ? 0u : srcp[t-1];
    for (int c = 0; c < chunk; ++c){
        int i = i0 + c;
        if (i < RB){ offs[(size_t)i*NB + b] = run; run += sv[i]; }
    }
    if (t == 255) gcount[b] = srcp[255];
}

// --------- route: deterministic binned scatter of PACKED u32 entries (localj:9 | k:5 | i:16) ---------
// Shfl-based 512-bin scan (2 barriers instead of 10); LDS 22 KB -> 7 blocks/CU.
__global__ void __launch_bounds__(256) k_route(
    const int* __restrict__ pin, const int* __restrict__ pout,
    const unsigned* __restrict__ offs, const unsigned* __restrict__ histR,
    unsigned* __restrict__ staging, int E, int P, int NB)
{
    __shared__ unsigned gbase[512];
    __shared__ unsigned lbase[512];
    __shared__ unsigned rank2[512];
    __shared__ unsigned wtot[4];
    __shared__ unsigned s_dst[ECH];
    __shared__ unsigned s_u[ECH];

    int t = threadIdx.x, blk = blockIdx.x;
    int lane = t & 63, wid = t >> 6;
    int b0 = 2*t, b1 = 2*t + 1;
    unsigned v0 = (b0 < NB) ? histR[(size_t)blk*NB + b0] : 0u;
    unsigned v1 = (b1 < NB) ? histR[(size_t)blk*NB + b1] : 0u;
    gbase[b0] = (b0 < NB) ? offs[(size_t)blk*NB + b0] : 0u;
    gbase[b1] = (b1 < NB) ? offs[(size_t)blk*NB + b1] : 0u;
    rank2[b0] = 0u; rank2[b1] = 0u;
    unsigned s = v0 + v1;
    unsigned si = s;
    #pragma unroll
    for (int off = 1; off < 64; off <<= 1){
        unsigned u = __shfl_up(si, off);
        if (lane >= off) si += u;
    }
    if (lane == 63) wtot[wid] = si;
    __syncthreads();
    unsigned basew = 0u;
    #pragma unroll
    for (int ww = 0; ww < 4; ++ww) if (ww < wid) basew += wtot[ww];
    unsigned excl = basew + si - s;
    lbase[b0] = excl;
    lbase[b1] = excl + v0;

    int e0 = blk * ECH;
    int k0 = e0 / P;                 // one divide per thread (ECH < P)
    int rem0 = e0 - k0*P;
    __syncthreads();

    // pass B: assign deterministic slots, pack (localj,k,i) into 32 bits
    #pragma unroll
    for (int r = 0; r < ECH/256; ++r){
        int L = r*256 + t;
        int e = e0 + L;
        if (e < E){
            int j = pout[e];
            int i = pin[e];
            int b = j >> BINSH;
            int k = k0 + ((rem0 + L >= P) ? 1 : 0);
            unsigned rk = atomicAdd(&rank2[b], 1u);
            unsigned slot = lbase[b] + rk;
            unsigned d = gbase[b] + rk;
            if (d < BCAP){
                s_u[slot] = ((unsigned)(j & (BINW-1)) << 21) |
                            ((unsigned)k << 16) | (unsigned)i;
                s_dst[slot] = (unsigned)b*BCAP + d;
            } else {
                s_dst[slot] = 0xFFFFFFFFu;   // statistically impossible overflow: drop
            }
        }
    }
    __syncthreads();

    // pass C: coalesced flush of bin-ordered runs
    int nval = min(ECH, E - e0);
    for (int idx = t; idx < nval; idx += 256){
        unsigned d = s_dst[idx];
        if (d != 0xFFFFFFFFu) staging[d] = s_u[idx];
    }
}

// --------- back: bin accumulate FUSED with the final gated product; 2 blocks per bin ---------
// Each block owns 256 of its bin's 512 rows (filter on localj bit 8): Ab LDS halves
// -> 4 blocks/CU and 782 blocks for the latency-bound w-gather phase.
__global__ void __launch_bounds__(256) k_back(
    const unsigned* __restrict__ gcount, const unsigned* __restrict__ staging,
    const float* __restrict__ w, const float* __restrict__ scsh,
    const float* __restrict__ x, const float* __restrict__ Winv,
    const float* __restrict__ binv,
    float* __restrict__ out, int Nx, int K)
{
    __shared__ float Ab[256*ASTRIDE];    // 28672 B
    __shared__ float Wl[27*64];          // 6912 B [k][c]
    __shared__ float bl[64];
    int t = threadIdx.x;
    int b = blockIdx.x >> 1;
    unsigned hbit = (blockIdx.x & 1) << 8;
    for (int i = t; i < 256*ASTRIDE/4; i += 256)
        ((float4*)Ab)[i] = make_float4(0.f,0.f,0.f,0.f);
    for (int idx = t; idx < 27*64/4; idx += 256)
        ((float4*)Wl)[idx] = ((const float4*)Winv)[idx];
    if (t < 64) bl[t] = binv[t];
    __syncthreads();

    float sc = scsh[0], sh = scsh[1];
    unsigned n = gcount[b]; if (n > BCAP) n = BCAP;
    const unsigned* sp = staging + (size_t)b*BCAP;
    unsigned n4 = n & ~3u;
    for (unsigned base = 4u*(unsigned)t; base < n4; base += 1024u){
        uint4 e4 = *(const uint4*)(sp + base);
        unsigned lj0 = e4.x >> 21, lj1 = e4.y >> 21, lj2 = e4.z >> 21, lj3 = e4.w >> 21;
        if ((lj0 & 256u) == hbit){
            float a0 = 1.0f/(1.0f+__expf(-fmaf(sc, w[e4.x & 0xFFFFu], sh)));
            atomicAdd(&Ab[(lj0 & 255u)*ASTRIDE + ((e4.x >> 16) & 31u)], a0);
        }
        if ((lj1 & 256u) == hbit){
            float a1 = 1.0f/(1.0f+__expf(-fmaf(sc, w[e4.y & 0xFFFFu], sh)));
            atomicAdd(&Ab[(lj1 & 255u)*ASTRIDE + ((e4.y >> 16) & 31u)], a1);
        }
        if ((lj2 & 256u) == hbit){
            float a2 = 1.0f/(1.0f+__expf(-fmaf(sc, w[e4.z & 0xFFFFu], sh)));
            atomicAdd(&Ab[(lj2 & 255u)*ASTRIDE + ((e4.z >> 16) & 31u)], a2);
        }
        if ((lj3 & 256u) == hbit){
            float a3 = 1.0f/(1.0f+__expf(-fmaf(sc, w[e4.w & 0xFFFFu], sh)));
            atomicAdd(&Ab[(lj3 & 255u)*ASTRIDE + ((e4.w >> 16) & 31u)], a3);
        }
    }
    for (unsigned idx = n4 + t; idx < n; idx += 256){
        unsigned e = sp[idx];
        unsigned lj = e >> 21;
        if ((lj & 256u) == hbit){
            float att = 1.0f/(1.0f+__expf(-fmaf(sc, w[e & 0xFFFFu], sh)));
            atomicAdd(&Ab[(lj & 255u)*ASTRIDE + ((e >> 16) & 31u)], att);
        }
    }
    __syncthreads();

    // final gated product for this half-bin's 256 rows (4 chunks of 64)
    int j0 = b * BINW + (int)(hbit >> 8) * 256;
    int cc = (t & 15) * 4;
    int jb = t >> 4;
    float4 b4 = ld4(&bl[cc]);
    for (int q0 = 0; q0 < 4; ++q0){
        float4 acc[4];
        #pragma unroll
        for (int q=0;q<4;q++) acc[q] = b4;
        for (int k=0;k<K;k++){
            float4 wv = ld4(&Wl[k*64 + cc]);
            #pragma unroll
            for (int q=0;q<4;q++){
                float a = Ab[(q0*64 + q*16 + jb)*ASTRIDE + k];
                acc[q].x = fmaf(a, wv.x, acc[q].x);
                acc[q].y = fmaf(a, wv.y, acc[q].y);
                acc[q].z = fmaf(a, wv.z, acc[q].z);
                acc[q].w = fmaf(a, wv.w, acc[q].w);
            }
        }
        #pragma unroll
        for (int q=0;q<4;q++){
            int j = j0 + q0*64 + q*16 + jb;
            if (j < Nx){
                float4 xv = ld4(x + (size_t)j*CS + cc);
                st4(out + (size_t)j*CS + cc,
                    make_float4(xv.x*acc[q].x, xv.y*acc[q].y, xv.z*acc[q].z, xv.w*acc[q].w));
            }
        }
    }
}

extern "C" void kernel_launch(void* const* d_in, const int* in_sizes, int n_in,
                              void* d_out, int out_size, void* d_ws, size_t ws_size,
                              hipStream_t stream)
{
    const float* g        = (const float*)d_in[0];
    const float* x        = (const float*)d_in[1];
    const int*   down_idx = (const int*)d_in[2];
    const int*   pin      = (const int*)d_in[3];
    const int*   pout     = (const int*)d_in[4];
    const float* Wg       = (const float*)d_in[5];
    const float* Ws       = (const float*)d_in[6];
    const float* Wc       = (const float*)d_in[7];
    const float* Winv     = (const float*)d_in[8];
    const float* binv     = (const float*)d_in[9];
    const float* gamma_g  = (const float*)d_in[10];
    const float* beta_g   = (const float*)d_in[11];
    const float* gamma_s  = (const float*)d_in[12];
    const float* beta_s   = (const float*)d_in[13];
    const float* gamma_c  = (const float*)d_in[14];
    const float* beta_c   = (const float*)d_in[15];

    int Ng = in_sizes[0] / CG;       // 60000 (< 65536: packed-entry requirement)
    int Nx = in_sizes[1] / CS;       // 200000
    int K  = in_sizes[8] / CS;       // 27
    int P  = in_sizes[3] / K;        // 100000
    int E  = K * P;                  // 2.7M
    int NB = (Nx + BINW - 1) >> BINSH; // 391 bins
    int RB = (E + ECH - 1) / ECH;      // 1319 hist/route blocks
    int GB = (Ng + GROWS - 1) / GROWS; // 469 gemm blocks per branch
    int fb = (Ng + FROWS - 1) / FROWS; // 938 fuse blocks

    float* ws = (float*)d_ws;
    size_t offStats = 0;
    size_t offScsh  = offStats + 512;             // 16
    size_t offGc    = offScsh + 16;               // gcount: 512
    size_t offWp    = offGc + 512;                // wpart: 2048
    size_t offYg    = offWp + 2048;
    size_t offYs    = offYg + (size_t)Ng*CN;
    size_t offW     = offYs + (size_t)Ng*CN;
    size_t offHR    = offW + (size_t)Ng;          // histR: RB*NB uint
    size_t offHT    = offHR + (size_t)RB*NB;      // histT: RB*NB uint
    size_t offOf    = offHT + (size_t)RB*NB;      // offs:  RB*NB uint

    float* stats  = ws + offStats;
    float* scsh   = ws + offScsh;
    unsigned* gcount = (unsigned*)(ws + offGc);
    float* wpart  = ws + offWp;
    float* Yg     = ws + offYg;
    float* Ys     = ws + offYs;
    float* wbuf   = ws + offW;
    unsigned* histR = (unsigned*)(ws + offHR);
    unsigned* histT = (unsigned*)(ws + offHT);
    unsigned* offsb = (unsigned*)(ws + offOf);
    // staging aliases Yg (dead after k_fuse): NB*BCAP u32 = 3.2M u32 <= Ng*CN = 3.84M floats
    unsigned* staging = (unsigned*)(ws + offYg);

    // zero only the gemm-stats accumulators
    hipMemsetAsync(stats, 0, 512 * sizeof(float), stream);

    k_front<<<2*GB + RB, 256, 0, stream>>>(g, x, down_idx, Wg, Ws, Yg, Ys, stats,
                                           pout, histR, histT, Ng, E, NB, RB, GB);
    k_fuse<<<fb, 256, 0, stream>>>(Yg, Ys, stats, gamma_g, beta_g,
                                   gamma_s, beta_s, Wc, wbuf, wpart, Ng);
    k_offs<<<NB+1, 256, 0, stream>>>(histT, offsb, gcount, wpart, fb,
                                     gamma_c, beta_c, scsh, RB, NB, Ng);
    k_route<<<RB, 256, 0, stream>>>(pin, pout, offsb, histR, staging, E, P, NB);
    k_back<<<2*NB, 256, 0, stream>>>(gcount, staging, wbuf, scsh,
                                     x, Winv, binv, (float*)d_out, Nx, K);
}